// Round 2
// baseline (6710.474 us; speedup 1.0000x reference)
//
#include <hip/hip_runtime.h>

#define STEPS 30
#define HID 32
#define BLK 256

// fused-weight float offsets in g_ws
#define OFF_WRZ 0      // 64x32: Wih[r][2+k] + Whh[r][k], rows 0..63 (r then z gates)
#define OFF_CRZ 2048   // 64x4 : [Wih[r][0], Wih[r][1], bih[r]+bhh[r], 0]
#define OFF_WIN 2304   // 32x32: Wih[64+i][2+k]
#define OFF_CIN 3328   // 32x4 : [Wih[64+i][0], Wih[64+i][1], bih[64+i], bhh[64+i]]
#define OFF_WHN 3456   // 32x32: Whh[64+i][k]
#define OFF_W1H 4480   // 32x32: W1[i][2+k]
#define OFF_C1  5504   // 32x4 : [W1[i][0], W1[i][1], b1[i], W2[i]]
#define OFF_B2  5632   // 1
#define WTOT    5636   // padded to 16B multiple

__device__ float g_ws[WTOT];

__global__ void fuse_weights_k(const float* __restrict__ W1, const float* __restrict__ b1,
                               const float* __restrict__ W2, const float* __restrict__ b2,
                               const float* __restrict__ Wih, const float* __restrict__ bih,
                               const float* __restrict__ Whh, const float* __restrict__ bhh) {
  const int t = threadIdx.x;
  for (int idx = t; idx < 64 * 32; idx += blockDim.x) {
    int r = idx >> 5, k = idx & 31;
    g_ws[OFF_WRZ + idx] = Wih[r * 34 + 2 + k] + Whh[r * 32 + k];
  }
  for (int r = t; r < 64; r += blockDim.x) {
    g_ws[OFF_CRZ + 4 * r + 0] = Wih[r * 34 + 0];
    g_ws[OFF_CRZ + 4 * r + 1] = Wih[r * 34 + 1];
    g_ws[OFF_CRZ + 4 * r + 2] = bih[r] + bhh[r];
    g_ws[OFF_CRZ + 4 * r + 3] = 0.f;
  }
  for (int idx = t; idx < 32 * 32; idx += blockDim.x) {
    int i = idx >> 5, k = idx & 31;
    g_ws[OFF_WIN + idx] = Wih[(64 + i) * 34 + 2 + k];
    g_ws[OFF_WHN + idx] = Whh[(64 + i) * 32 + k];
    g_ws[OFF_W1H + idx] = W1[i * 34 + 2 + k];
  }
  for (int i = t; i < 32; i += blockDim.x) {
    g_ws[OFF_CIN + 4 * i + 0] = Wih[(64 + i) * 34 + 0];
    g_ws[OFF_CIN + 4 * i + 1] = Wih[(64 + i) * 34 + 1];
    g_ws[OFF_CIN + 4 * i + 2] = bih[64 + i];
    g_ws[OFF_CIN + 4 * i + 3] = bhh[64 + i];
    g_ws[OFF_C1 + 4 * i + 0] = W1[i * 34 + 0];
    g_ws[OFF_C1 + 4 * i + 1] = W1[i * 34 + 1];
    g_ws[OFF_C1 + 4 * i + 2] = b1[i];
    g_ws[OFF_C1 + 4 * i + 3] = W2[i];
  }
  if (t == 0) g_ws[OFF_B2] = b2[0];
}

__device__ __forceinline__ float sigm_f(float x) {
  return __builtin_amdgcn_rcpf(1.f + __expf(-x));
}
__device__ __forceinline__ float tanh_f(float x) {
  float e = __expf(2.f * x);
  return 1.f - 2.f * __builtin_amdgcn_rcpf(e + 1.f);
}

__global__ __launch_bounds__(BLK, 2)
void hedge_k(const float* __restrict__ S, float* __restrict__ out) {
  // weights: wave-uniform broadcast reads from LDS (no bank traffic)
  __shared__ __align__(16) float w[WTOT];
  // per-thread h copy for the one dynamic index h[i] in the GRU blend.
  // layout [i][tid]: lanes contiguous -> conflict-free
  __shared__ float hbuf[HID * BLK];

  for (int i = threadIdx.x; i < WTOT; i += BLK) w[i] = g_ws[i];
  __syncthreads();

  const int b = blockIdx.x * BLK + threadIdx.x;
  const float* sp = S + (size_t)b * (STEPS + 1);
  float* op = out + (size_t)b * STEPS;

  float h[HID];
#pragma unroll
  for (int k = 0; k < HID; ++k) { h[k] = 0.f; hbuf[k * BLK + threadIdx.x] = 0.f; }
  float delta = 0.f;
  const float b2v = w[OFF_B2];

  float s_cur = sp[0];
#pragma unroll 1
  for (int t = 0; t < STEPS; ++t) {
    const float s_nxt = sp[(t < STEPS - 1) ? (t + 1) : t];  // prefetch, hidden under body
    const float s = s_cur;

    // ---- shared MLP: delta_new = b2 + sum_i relu(row_i . x) * W2[i] ----
    float dnew = b2v;
#pragma unroll 1
    for (int i = 0; i < HID; ++i) {
      const float4 c = *reinterpret_cast<const float4*>(&w[OFF_C1 + 4 * i]);
      const float* wr = &w[OFF_W1H + i * HID];
      float a0 = fmaf(s, c.x, fmaf(delta, c.y, c.z));
      float a1 = 0.f;
#pragma unroll
      for (int k = 0; k < HID; k += 8) {
        float4 u = *reinterpret_cast<const float4*>(&wr[k]);
        float4 v = *reinterpret_cast<const float4*>(&wr[k + 4]);
        a0 = fmaf(h[k + 0], u.x, a0);
        a0 = fmaf(h[k + 1], u.y, a0);
        a0 = fmaf(h[k + 2], u.z, a0);
        a0 = fmaf(h[k + 3], u.w, a0);
        a1 = fmaf(h[k + 4], v.x, a1);
        a1 = fmaf(h[k + 5], v.y, a1);
        a1 = fmaf(h[k + 6], v.z, a1);
        a1 = fmaf(h[k + 7], v.w, a1);
      }
      float a = fmaxf(a0 + a1, 0.f);
      dnew = fmaf(a, c.w, dnew);
    }

    // ---- GRU gates (torch order r,z,n); r/z use pre-summed gi+gh weights ----
#pragma unroll 1
    for (int i = 0; i < HID; ++i) {
      const float4 cr = *reinterpret_cast<const float4*>(&w[OFF_CRZ + 4 * i]);
      const float4 cz = *reinterpret_cast<const float4*>(&w[OFF_CRZ + 4 * (HID + i)]);
      const float4 cn = *reinterpret_cast<const float4*>(&w[OFF_CIN + 4 * i]);
      const float* wr = &w[OFF_WRZ + i * HID];
      const float* wz = &w[OFF_WRZ + (HID + i) * HID];
      const float* wi = &w[OFF_WIN + i * HID];
      const float* wh = &w[OFF_WHN + i * HID];
      float ar = fmaf(s, cr.x, fmaf(delta, cr.y, cr.z));
      float az = fmaf(s, cz.x, fmaf(delta, cz.y, cz.z));
      float an = fmaf(s, cn.x, fmaf(delta, cn.y, cn.z));
      float ah = cn.w;  // bhh[64+i]
#pragma unroll
      for (int k = 0; k < HID; k += 4) {
        float4 u = *reinterpret_cast<const float4*>(&wr[k]);
        float4 v = *reinterpret_cast<const float4*>(&wz[k]);
        float4 p = *reinterpret_cast<const float4*>(&wi[k]);
        float4 q = *reinterpret_cast<const float4*>(&wh[k]);
        ar = fmaf(h[k + 0], u.x, ar);
        ar = fmaf(h[k + 1], u.y, ar);
        ar = fmaf(h[k + 2], u.z, ar);
        ar = fmaf(h[k + 3], u.w, ar);
        az = fmaf(h[k + 0], v.x, az);
        az = fmaf(h[k + 1], v.y, az);
        az = fmaf(h[k + 2], v.z, az);
        az = fmaf(h[k + 3], v.w, az);
        an = fmaf(h[k + 0], p.x, an);
        an = fmaf(h[k + 1], p.y, an);
        an = fmaf(h[k + 2], p.z, an);
        an = fmaf(h[k + 3], p.w, an);
        ah = fmaf(h[k + 0], q.x, ah);
        ah = fmaf(h[k + 1], q.y, ah);
        ah = fmaf(h[k + 2], q.z, ah);
        ah = fmaf(h[k + 3], q.w, ah);
      }
      float r = sigm_f(ar);
      float z = sigm_f(az);
      float n = tanh_f(fmaf(r, ah, an));
      float hold = hbuf[i * BLK + threadIdx.x];          // == h[i] (old)
      hbuf[i * BLK + threadIdx.x] = fmaf(z, hold - n, n); // (1-z)*n + z*h
    }

    // ---- write back new h into registers (static indices) ----
#pragma unroll
    for (int k = 0; k < HID; ++k) h[k] = hbuf[k * BLK + threadIdx.x];

    delta = dnew;
    op[t] = dnew;
    s_cur = s_nxt;
  }
}

extern "C" void kernel_launch(void* const* d_in, const int* in_sizes, int n_in,
                              void* d_out, int out_size, void* d_ws, size_t ws_size,
                              hipStream_t stream) {
  const float* S   = (const float*)d_in[0];
  const float* W1  = (const float*)d_in[1];
  const float* b1  = (const float*)d_in[2];
  const float* W2  = (const float*)d_in[3];
  const float* b2  = (const float*)d_in[4];
  const float* Wih = (const float*)d_in[5];
  const float* bih = (const float*)d_in[6];
  const float* Whh = (const float*)d_in[7];
  const float* bhh = (const float*)d_in[8];
  float* out = (float*)d_out;

  const int batch = in_sizes[0] / (STEPS + 1);

  fuse_weights_k<<<1, 256, 0, stream>>>(W1, b1, W2, b2, Wih, bih, Whh, bhh);
  hedge_k<<<batch / BLK, BLK, 0, stream>>>(S, out);
}

// Round 3
// 5394.917 us; speedup vs baseline: 1.2439x; 1.2439x over previous
//
#include <hip/hip_runtime.h>

#define STEPS 30
#define HID 32
#define BLK 256

// fused-weight float offsets in gw (workspace)
#define OFF_WRZ 0      // 64x32: Wih[r][2+k] + Whh[r][k], rows 0..63 (r then z gates)
#define OFF_CRZ 2048   // 64x4 : [Wih[r][0], Wih[r][1], bih[r]+bhh[r], 0]
#define OFF_WIN 2304   // 32x32: Wih[64+i][2+k]
#define OFF_CIN 3328   // 32x4 : [Wih[64+i][0], Wih[64+i][1], bih[64+i], bhh[64+i]]
#define OFF_WHN 3456   // 32x32: Whh[64+i][k]
#define OFF_W1H 4480   // 32x32: W1[i][2+k]
#define OFF_C1  5504   // 32x4 : [W1[i][0], W1[i][1], b1[i], W2[i]]
#define OFF_B2  5632   // 1
#define WTOT    5636

__device__ float g_ws[WTOT];  // fallback if d_ws too small

__global__ void fuse_weights_k(float* __restrict__ gw,
                               const float* __restrict__ W1, const float* __restrict__ b1,
                               const float* __restrict__ W2, const float* __restrict__ b2,
                               const float* __restrict__ Wih, const float* __restrict__ bih,
                               const float* __restrict__ Whh, const float* __restrict__ bhh) {
  const int t = threadIdx.x;
  for (int idx = t; idx < 64 * 32; idx += blockDim.x) {
    int r = idx >> 5, k = idx & 31;
    gw[OFF_WRZ + idx] = Wih[r * 34 + 2 + k] + Whh[r * 32 + k];
  }
  for (int r = t; r < 64; r += blockDim.x) {
    gw[OFF_CRZ + 4 * r + 0] = Wih[r * 34 + 0];
    gw[OFF_CRZ + 4 * r + 1] = Wih[r * 34 + 1];
    gw[OFF_CRZ + 4 * r + 2] = bih[r] + bhh[r];
    gw[OFF_CRZ + 4 * r + 3] = 0.f;
  }
  for (int idx = t; idx < 32 * 32; idx += blockDim.x) {
    int i = idx >> 5, k = idx & 31;
    gw[OFF_WIN + idx] = Wih[(64 + i) * 34 + 2 + k];
    gw[OFF_WHN + idx] = Whh[(64 + i) * 32 + k];
    gw[OFF_W1H + idx] = W1[i * 34 + 2 + k];
  }
  for (int i = t; i < 32; i += blockDim.x) {
    gw[OFF_CIN + 4 * i + 0] = Wih[(64 + i) * 34 + 0];
    gw[OFF_CIN + 4 * i + 1] = Wih[(64 + i) * 34 + 1];
    gw[OFF_CIN + 4 * i + 2] = bih[64 + i];
    gw[OFF_CIN + 4 * i + 3] = bhh[64 + i];
    gw[OFF_C1 + 4 * i + 0] = W1[i * 34 + 0];
    gw[OFF_C1 + 4 * i + 1] = W1[i * 34 + 1];
    gw[OFF_C1 + 4 * i + 2] = b1[i];
    gw[OFF_C1 + 4 * i + 3] = W2[i];
  }
  if (t == 0) gw[OFF_B2] = b2[0];
}

__device__ __forceinline__ float sigm_f(float x) {
  return __builtin_amdgcn_rcpf(1.f + __expf(-x));
}
__device__ __forceinline__ float tanh_f(float x) {
  float e = __expf(2.f * x);
  return 1.f - 2.f * __builtin_amdgcn_rcpf(e + 1.f);
}

// Weights read via wave-uniform indices from a const __restrict__ pointer ->
// compiler selects s_load (constant cache, scalar pipe), and v_fma_f32 takes
// the weight as its single SGPR operand. LDS holds ONLY the per-thread h
// column (dynamic index h[i] in the GRU blend); no barriers needed.
__global__ __launch_bounds__(BLK, 4)
void hedge_k(const float* __restrict__ S, const float* __restrict__ gw,
             float* __restrict__ out) {
  __shared__ float hbuf[HID * BLK];  // 32 KB: [i][tid], own-column only

  const int b = blockIdx.x * BLK + threadIdx.x;
  const float* sp = S + (size_t)b * (STEPS + 1);
  float* op = out + (size_t)b * STEPS;

  float h[HID];
#pragma unroll
  for (int k = 0; k < HID; ++k) { h[k] = 0.f; hbuf[k * BLK + threadIdx.x] = 0.f; }
  float delta = 0.f;
  const float b2v = gw[OFF_B2];

  float s_cur = sp[0];
  float d_even = 0.f;  // pairs output stores into aligned float2 (b*120 + t*4, t even -> 8B aligned)
#pragma unroll 1
  for (int t = 0; t < STEPS; ++t) {
    const float s_nxt = sp[(t < STEPS - 1) ? (t + 1) : t];
    const float s = s_cur;

    // ---- shared MLP: delta_new = b2 + sum_i relu(row_i . x) * W2[i] ----
    float dnew = b2v;
#pragma unroll 2
    for (int i = 0; i < HID; ++i) {
      const float* c  = &gw[OFF_C1 + 4 * i];
      const float* wr = &gw[OFF_W1H + i * HID];
      float a0 = fmaf(s, c[0], fmaf(delta, c[1], c[2]));
      float a1 = 0.f;
#pragma unroll
      for (int k = 0; k < HID; k += 2) {
        a0 = fmaf(h[k + 0], wr[k + 0], a0);
        a1 = fmaf(h[k + 1], wr[k + 1], a1);
      }
      float a = fmaxf(a0 + a1, 0.f);
      dnew = fmaf(a, c[3], dnew);
    }

    // ---- GRU gates (torch order r,z,n); r/z use pre-summed gi+gh weights ----
#pragma unroll 2
    for (int i = 0; i < HID; ++i) {
      const float* cr = &gw[OFF_CRZ + 4 * i];
      const float* cz = &gw[OFF_CRZ + 4 * (HID + i)];
      const float* cn = &gw[OFF_CIN + 4 * i];
      const float* wr = &gw[OFF_WRZ + i * HID];
      const float* wz = &gw[OFF_WRZ + (HID + i) * HID];
      const float* wi = &gw[OFF_WIN + i * HID];
      const float* wh = &gw[OFF_WHN + i * HID];
      float ar = fmaf(s, cr[0], fmaf(delta, cr[1], cr[2]));
      float az = fmaf(s, cz[0], fmaf(delta, cz[1], cz[2]));
      float an = fmaf(s, cn[0], fmaf(delta, cn[1], cn[2]));
      float ah = cn[3];  // bhh[64+i]
#pragma unroll
      for (int k = 0; k < HID; ++k) {
        ar = fmaf(h[k], wr[k], ar);
        az = fmaf(h[k], wz[k], az);
        an = fmaf(h[k], wi[k], an);
        ah = fmaf(h[k], wh[k], ah);
      }
      float r = sigm_f(ar);
      float z = sigm_f(az);
      float n = tanh_f(fmaf(r, ah, an));
      float hold = hbuf[i * BLK + threadIdx.x];           // == h[i] (old)
      hbuf[i * BLK + threadIdx.x] = fmaf(z, hold - n, n); // (1-z)*n + z*h
    }

    // ---- write back new h into registers (static indices) ----
#pragma unroll
    for (int k = 0; k < HID; ++k) h[k] = hbuf[k * BLK + threadIdx.x];

    delta = dnew;
    if (t & 1) {
      float2 v = make_float2(d_even, dnew);
      *reinterpret_cast<float2*>(op + (t - 1)) = v;
    } else {
      d_even = dnew;
    }
    s_cur = s_nxt;
  }
}

extern "C" void kernel_launch(void* const* d_in, const int* in_sizes, int n_in,
                              void* d_out, int out_size, void* d_ws, size_t ws_size,
                              hipStream_t stream) {
  const float* S   = (const float*)d_in[0];
  const float* W1  = (const float*)d_in[1];
  const float* b1  = (const float*)d_in[2];
  const float* W2  = (const float*)d_in[3];
  const float* b2  = (const float*)d_in[4];
  const float* Wih = (const float*)d_in[5];
  const float* bih = (const float*)d_in[6];
  const float* Whh = (const float*)d_in[7];
  const float* bhh = (const float*)d_in[8];
  float* out = (float*)d_out;

  const int batch = in_sizes[0] / (STEPS + 1);

  float* gw;
  if (ws_size >= WTOT * sizeof(float)) {
    gw = (float*)d_ws;
  } else {
    void* sym = nullptr;
    hipGetSymbolAddress(&sym, HIP_SYMBOL(g_ws));  // query only; graph-safe
    gw = (float*)sym;
  }

  fuse_weights_k<<<1, 256, 0, stream>>>(gw, W1, b1, W2, b2, Wih, bih, Whh, bhh);
  hedge_k<<<batch / BLK, BLK, 0, stream>>>(S, gw, out);
}

// Round 6
// 979.801 us; speedup vs baseline: 6.8488x; 5.5061x over previous
//
#include <hip/hip_runtime.h>

#define STEPS 30
#define HID 32
#define BLK 256
#define WPB 4           // waves per block
#define BPW 16          // batch elements per wave

typedef float  f32x4  __attribute__((ext_vector_type(4)));
typedef short  bf16x8 __attribute__((ext_vector_type(8)));

// gw layout in u32 units
#define GW_AH   0                    // 10 tiles * 64 lanes * 4 u32 (bf16x8 A-frags, h part, K-perm σ)
#define GW_ASD  2560                 // 10 tiles * 64 lanes * 4 u32 (A-frags for [s, delta, bias] in K=0..2)
#define GW_W2C  5120                 // 64 lanes * 8 f32 (W2 per C-row of the lane)
#define GW_B2   5632                 // 1 f32
#define GW_TOT  5633

__device__ uint g_ws_fallback[GW_TOT];

__device__ __forceinline__ float ex2(float x) {     // 2^x via v_exp_f32
  return __builtin_amdgcn_exp2f(x);
}

__device__ __forceinline__ ushort f2bf(float x) {   // f32 -> bf16 RNE
  uint u = __float_as_uint(x);
  return (ushort)((u + 0x7FFFu + ((u >> 16) & 1u)) >> 16);
}

// Build per-lane MFMA A-fragments directly in lane layout.
// A-frag (16x16x32 bf16): lane l holds row = l&15, k = (l>>4)*8 + e (e=0..7), bf16 pairs per u32.
// K-slot k holds h-dim sigma(k): sigma(8g+j) = (j<4) ? 4g+j : 16+4g+(j-4).
// This makes the C-layout h_new pack directly into the next B-frag (no cross-lane).
// Row scaling: r/z tiles by log2(e) (sigmoid via exp2), n tiles by 2*log2(e) (tanh via exp2), MLP by 1.
__global__ void prep_k(uint* __restrict__ gw,
                       const float* __restrict__ W1, const float* __restrict__ b1,
                       const float* __restrict__ W2, const float* __restrict__ b2,
                       const float* __restrict__ Wih, const float* __restrict__ bih,
                       const float* __restrict__ Whh, const float* __restrict__ bhh) {
  const float L2E = 1.44269504088896340736f;
  const float S2  = 2.0f * L2E;
  for (int idx = threadIdx.x; idx < 640; idx += blockDim.x) {
    const int T = idx >> 6, l = idx & 63;
    const int g = l >> 4, rr = l & 15;
    const int half = T & 1;
    int kd[8];
#pragma unroll
    for (int j = 0; j < 8; ++j) kd[j] = (j < 4) ? (4 * g + j) : (16 + 4 * g + (j - 4));
    float wk[8], Ws, Wd, Bc;
    if (T < 4) {                       // tiles 0-1: r gate, 2-3: z gate (Wih+Whh fused)
      const int R = (T >> 1) * 32 + half * 16 + rr;   // 0..63
#pragma unroll
      for (int j = 0; j < 8; ++j)
        wk[j] = (Wih[R * 34 + 2 + kd[j]] + Whh[R * 32 + kd[j]]) * L2E;
      Ws = Wih[R * 34 + 0] * L2E;
      Wd = Wih[R * 34 + 1] * L2E;
      Bc = (bih[R] + bhh[R]) * L2E;
    } else if (T < 6) {                // tiles 4-5: n input part (Wih_n)
      const int R = 64 + half * 16 + rr;
#pragma unroll
      for (int j = 0; j < 8; ++j) wk[j] = Wih[R * 34 + 2 + kd[j]] * S2;
      Ws = Wih[R * 34 + 0] * S2;
      Wd = Wih[R * 34 + 1] * S2;
      Bc = bih[R] * S2;
    } else if (T < 8) {                // tiles 6-7: n hidden part (Whh_n)
      const int R = 64 + half * 16 + rr;
#pragma unroll
      for (int j = 0; j < 8; ++j) wk[j] = Whh[R * 32 + kd[j]] * S2;
      Ws = 0.f; Wd = 0.f;
      Bc = bhh[R] * S2;
    } else {                           // tiles 8-9: MLP layer 1
      const int R = half * 16 + rr;    // 0..31
#pragma unroll
      for (int j = 0; j < 8; ++j) wk[j] = W1[R * 34 + 2 + kd[j]];
      Ws = W1[R * 34 + 0];
      Wd = W1[R * 34 + 1];
      Bc = b1[R];
    }
    uint* ah = gw + GW_AH + (size_t)(T * 64 + l) * 4;
#pragma unroll
    for (int p = 0; p < 4; ++p)
      ah[p] = (uint)f2bf(wk[2 * p]) | ((uint)f2bf(wk[2 * p + 1]) << 16);
    uint* asd = gw + GW_ASD + (size_t)(T * 64 + l) * 4;
    if (g == 0) {   // K slots 0,1,2 = [Ws, Wd, bias]; rest zero
      asd[0] = (uint)f2bf(Ws) | ((uint)f2bf(Wd) << 16);
      asd[1] = (uint)f2bf(Bc);
      asd[2] = 0u; asd[3] = 0u;
    } else {
      asd[0] = 0u; asd[1] = 0u; asd[2] = 0u; asd[3] = 0u;
    }
  }
  // W2 constants aligned to the lane's C-rows: lane (g,c) holds rows {4g+j}j<4 U {16+4g+j}
  for (int l = threadIdx.x; l < 64; l += blockDim.x) {
    const int g = l >> 4;
    float* w2c = (float*)(gw + GW_W2C) + l * 8;
#pragma unroll
    for (int j = 0; j < 8; ++j) {
      const int row = (j < 4) ? (4 * g + j) : (16 + 4 * g + (j - 4));
      w2c[j] = W2[row];
    }
  }
  if (threadIdx.x == 0) ((float*)gw)[GW_B2] = b2[0];
}

__global__ __launch_bounds__(BLK, 2)
void hedge_k(const float* __restrict__ S, const uint* __restrict__ gw,
             float* __restrict__ out) {
  __shared__ __align__(16) float dstage[WPB * BPW * STEPS];  // 1920 f32 = 7.5 KB

  const int tid = threadIdx.x;
  const int wave = tid >> 6, lane = tid & 63;
  const int g = lane >> 4, c = lane & 15;
  const int b0 = (blockIdx.x * WPB + wave) * BPW;

  union U { uint4 u; bf16x8 v; };

  // resident weight fragments: 80 VGPRs, loaded once
  bf16x8 ah[10], asd[10];
#pragma unroll
  for (int T = 0; T < 10; ++T) {
    U x; x.u = *(const uint4*)(gw + GW_AH  + (T * 64 + lane) * 4); ah[T]  = x.v;
    U y; y.u = *(const uint4*)(gw + GW_ASD + (T * 64 + lane) * 4); asd[T] = y.v;
  }
  float w2c[8];
  {
    const float4 a = *(const float4*)((const float*)(gw + GW_W2C) + lane * 8);
    const float4 b = *(const float4*)((const float*)(gw + GW_W2C) + lane * 8 + 4);
    w2c[0] = a.x; w2c[1] = a.y; w2c[2] = a.z; w2c[3] = a.w;
    w2c[4] = b.x; w2c[5] = b.y; w2c[6] = b.z; w2c[7] = b.w;
  }
  const float b2v = ((const float*)gw)[GW_B2];
  const bool isg0 = (g == 0);

  const float* sp = S + (size_t)(b0 + c) * (STEPS + 1);

  float hold[8];
#pragma unroll
  for (int j = 0; j < 8; ++j) hold[j] = 0.f;
  bf16x8 bh;
  { U z; z.u.x = 0u; z.u.y = 0u; z.u.z = 0u; z.u.w = 0u; bh = z.v; }
  float delta = 0.f;
  const f32x4 zero4 = {0.f, 0.f, 0.f, 0.f};

  float s_cur = sp[0];
#pragma unroll 1
  for (int t = 0; t < STEPS; ++t) {
    const float s_nxt = sp[(t < STEPS - 1) ? (t + 1) : t];

    // B-frag for [s, delta, 1] rank-3 update: only group-0 lanes (K=0..7) nonzero
    uint pk;
    asm("v_cvt_pk_bf16_f32 %0, %1, %2" : "=v"(pk) : "v"(s_cur), "v"(delta));
    U bz;
    bz.u.x = isg0 ? pk : 0u;
    bz.u.y = isg0 ? 0x3F80u : 0u;   // bf16(1.0) in K=2, 0 in K=3
    bz.u.z = 0u; bz.u.w = 0u;
    const bf16x8 bsd = bz.v;

    f32x4 acc[10];
#pragma unroll
    for (int T = 0; T < 10; ++T)
      acc[T] = __builtin_amdgcn_mfma_f32_16x16x32_bf16(asd[T], bsd, zero4, 0, 0, 0);
#pragma unroll
    for (int T = 0; T < 10; ++T)
      acc[T] = __builtin_amdgcn_mfma_f32_16x16x32_bf16(ah[T], bh, acc[T], 0, 0, 0);

    // lane-local elementwise: lane holds slots j=0..7 (same batch c, dims sigma(8g+j))
    float dacc0 = 0.f, dacc1 = 0.f;
#pragma unroll
    for (int j = 0; j < 8; ++j) {
      const int tb = (j < 4) ? 0 : 1;
      const int r = j & 3;
      const float rpre = acc[0 + tb][r];   // pre-scaled by log2e
      const float zpre = acc[2 + tb][r];
      const float nipre = acc[4 + tb][r];  // pre-scaled by 2*log2e
      const float nhpre = acc[6 + tb][r];
      const float mpre = acc[8 + tb][r];
      const float rv = __builtin_amdgcn_rcpf(1.f + ex2(-rpre));
      const float zv = __builtin_amdgcn_rcpf(1.f + ex2(-zpre));
      const float npre = fmaf(rv, nhpre, nipre);
      const float nv = fmaf(-2.f, __builtin_amdgcn_rcpf(ex2(npre) + 1.f), 1.f);
      const float hv = fmaf(zv, hold[j] - nv, nv);   // (1-z)n + z*h
      hold[j] = hv;
      const float mv = fmaxf(mpre, 0.f);
      if (j & 1) dacc1 = fmaf(mv, w2c[j], dacc1);
      else       dacc0 = fmaf(mv, w2c[j], dacc0);
    }

    // pack h_new into next B-frag: slot order == k order, pure lane-local
    uint p0, p1, p2, p3;
    asm("v_cvt_pk_bf16_f32 %0, %1, %2" : "=v"(p0) : "v"(hold[0]), "v"(hold[1]));
    asm("v_cvt_pk_bf16_f32 %0, %1, %2" : "=v"(p1) : "v"(hold[2]), "v"(hold[3]));
    asm("v_cvt_pk_bf16_f32 %0, %1, %2" : "=v"(p2) : "v"(hold[4]), "v"(hold[5]));
    asm("v_cvt_pk_bf16_f32 %0, %1, %2" : "=v"(p3) : "v"(hold[6]), "v"(hold[7]));
    { U nb; nb.u.x = p0; nb.u.y = p1; nb.u.z = p2; nb.u.w = p3; bh = nb.v; }

    // MLP reduce across the 4 lane-groups holding the same batch element
    float d = dacc0 + dacc1;
    d += __shfl_xor(d, 16, 64);
    d += __shfl_xor(d, 32, 64);
    delta = d + b2v;

    if (isg0) dstage[(wave * BPW + c) * STEPS + t] = delta;
    s_cur = s_nxt;
  }

  __syncthreads();
  // coalesced flush: block's output region is contiguous (64 batch * 30 steps)
  float4* o4 = (float4*)(out + (size_t)blockIdx.x * (WPB * BPW * STEPS));
  const float4* l4 = (const float4*)dstage;
  for (int i = tid; i < (WPB * BPW * STEPS) / 4; i += BLK) o4[i] = l4[i];
}

extern "C" void kernel_launch(void* const* d_in, const int* in_sizes, int n_in,
                              void* d_out, int out_size, void* d_ws, size_t ws_size,
                              hipStream_t stream) {
  const float* S   = (const float*)d_in[0];
  const float* W1  = (const float*)d_in[1];
  const float* b1  = (const float*)d_in[2];
  const float* W2  = (const float*)d_in[3];
  const float* b2  = (const float*)d_in[4];
  const float* Wih = (const float*)d_in[5];
  const float* bih = (const float*)d_in[6];
  const float* Whh = (const float*)d_in[7];
  const float* bhh = (const float*)d_in[8];
  float* out = (float*)d_out;

  const int batch = in_sizes[0] / (STEPS + 1);

  uint* gw;
  if (ws_size >= GW_TOT * sizeof(uint)) {
    gw = (uint*)d_ws;
  } else {
    void* sym = nullptr;
    (void)hipGetSymbolAddress(&sym, HIP_SYMBOL(g_ws_fallback));
    gw = (uint*)sym;
  }

  prep_k<<<1, 256, 0, stream>>>(gw, W1, b1, W2, b2, Wih, bih, Whh, bhh);
  hedge_k<<<batch / (WPB * BPW), BLK, 0, stream>>>(S, gw, out);
}